// Round 11
// baseline (30785.446 us; speedup 1.0000x reference)
//
#include <hip/hip_runtime.h>
#include <hip/hip_bf16.h>
#include <cstdint>
#include <cstddef>

#define SEQ 4096
#define HID 1024
#define G4  4096
#define UPL 64

typedef float f32x4 __attribute__((ext_vector_type(4)));

// ---------------- persistent device scratch ------------------------------------
__device__ float g_xg  [(size_t)SEQ * G4];   // 64 MB: input preactivations
__device__ float g_y   [(size_t)SEQ * HID];  // 16 MB: bottom LSTM outputs
__device__ float g_hs  [(size_t)SEQ * HID];  // 16 MB: h per step (NaN-sentinel)
__device__ float g_upxs[(size_t)UPL * HID];  // sampled y rows (NaN-sentinel)
__device__ float g_h2s [(size_t)UPL * HID];  // top LSTM h per step (NaN-sentinel)
__device__ float g_bias2[HID];
__device__ float g_e[SEQ];
__device__ float g_p[SEQ];
__device__ float g_invden[SEQ];
__device__ float g_csum[64 * HID];

// NaN-fill all sentinel buffers each launch (kernel-boundary release/acquire
// makes the fill visible device-wide before k_lstm; no cross-call state).
__global__ __launch_bounds__(256) void k_init()
{
  const size_t i = (size_t)blockIdx.x * 256 + threadIdx.x;   // 1M threads
  const unsigned Q = 0x7fc00000u;
  const uint4 nan4v = {Q, Q, Q, Q};
  ((uint4*)g_hs)[i] = nan4v;                                 // exactly 16 MB
  if (i < (size_t)UPL * HID / 4) {
    ((uint4*)g_upxs)[i] = nan4v;
    ((uint4*)g_h2s)[i]  = nan4v;
  }
}

// -------- coherent ops at the chip coherence point ------------------------------
__device__ __forceinline__ void sc_store1(float* p, float v) {
  asm volatile("global_store_dword %0, %1, off sc0 sc1" :: "v"(p), "v"(v) : "memory");
}
__device__ __forceinline__ f32x4 sc_load4(const float* p) {
  f32x4 v;
  asm volatile("global_load_dwordx4 %0, %1, off sc0 sc1\n\t"
               "s_waitcnt vmcnt(0)" : "=&v"(v) : "v"(p));
  return v;
}
__device__ __forceinline__ int nan4(f32x4 c) {
  return (c.x != c.x) | (c.y != c.y) | (c.z != c.z) | (c.w != c.w);
}

__device__ __forceinline__ float dot_row(const f32x4* __restrict__ wv,
                                         const f32x4* __restrict__ hc) {
  f32x4 a = {0.f, 0.f, 0.f, 0.f};
#pragma unroll
  for (int k = 0; k < 16; k++) a += wv[k] * hc[k];
  return (a.x + a.y) + (a.z + a.w);
}

// Plain-load 16 chunks (fresh address -> coherent fill), FMA, single NaN check.
// Slow path: sc0sc1 reload of stale chunks (bypasses polluted L1/L2), recompute.
template<int SL>
__device__ __forceinline__ float poll_dot(const float* __restrict__ hb,
                                          const f32x4* __restrict__ wv, float add)
{
  if (SL) { __builtin_amdgcn_s_sleep(SL); asm volatile("" ::: "memory"); }
  f32x4 hc[16];
#pragma unroll
  for (int k = 0; k < 16; k++) hc[k] = *(const f32x4*)(hb + (k << 2));
  float acc = dot_row(wv, hc) + add;
  while (__any(acc != acc)) {
    __builtin_amdgcn_s_sleep(2);
#pragma unroll
    for (int k = 0; k < 16; k++) if (nan4(hc[k])) hc[k] = sc_load4(hb + (k << 2));
    acc = dot_row(wv, hc) + add;
  }
  return acc;
}

__device__ __forceinline__ void load_w16(f32x4* __restrict__ wv,
                                         const float* __restrict__ W,
                                         int row, int j)
{
  const float* wr = W + (size_t)row * HID + (j << 6);
#pragma unroll
  for (int k = 0; k < 16; k++) wv[k] = *(const f32x4*)&wr[k << 2];
}

// ---------------- K1: xg = x @ bot_Wih^T + (bih + bhh), fp32 tiled GEMM --------
#define BMT 128
#define BNT 128
#define BKT 32

__global__ __launch_bounds__(256) void k_gemm_xg(const float* __restrict__ A,
                                                 const float* __restrict__ B,
                                                 const float* __restrict__ bias0,
                                                 const float* __restrict__ bias1)
{
  __shared__ float As[BKT][BMT + 4];
  __shared__ float Bs[BKT][BNT + 4];
  const int t  = threadIdx.x;
  const int bn = blockIdx.x;
  const int bm = blockIdx.y;
  const int m0 = (t & 15) * 8;
  const int n0 = (t >> 4) * 8;

  float acc[8][8];
#pragma unroll
  for (int i = 0; i < 8; i++)
#pragma unroll
    for (int j = 0; j < 8; j++) acc[i][j] = 0.f;

  for (int k0 = 0; k0 < 1024; k0 += BKT) {
#pragma unroll
    for (int i = 0; i < 4; i++) {
      const int idx = i * 256 + t;
      const int m   = idx >> 3;
      const int k4  = (idx & 7) << 2;
      const float4 av = *(const float4*)&A[(size_t)(bm * BMT + m) * 1024 + k0 + k4];
      As[k4 + 0][m] = av.x; As[k4 + 1][m] = av.y; As[k4 + 2][m] = av.z; As[k4 + 3][m] = av.w;
      const float4 bv = *(const float4*)&B[(size_t)(bn * BNT + m) * 1024 + k0 + k4];
      Bs[k4 + 0][m] = bv.x; Bs[k4 + 1][m] = bv.y; Bs[k4 + 2][m] = bv.z; Bs[k4 + 3][m] = bv.w;
    }
    __syncthreads();
#pragma unroll
    for (int k = 0; k < BKT; k++) {
      float a[8], b[8];
      *(float4*)&a[0] = *(const float4*)&As[k][m0];
      *(float4*)&a[4] = *(const float4*)&As[k][m0 + 4];
      *(float4*)&b[0] = *(const float4*)&Bs[k][n0];
      *(float4*)&b[4] = *(const float4*)&Bs[k][n0 + 4];
#pragma unroll
      for (int i = 0; i < 8; i++)
#pragma unroll
        for (int j = 0; j < 8; j++) acc[i][j] = fmaf(a[i], b[j], acc[i][j]);
    }
    __syncthreads();
  }

  float bb[8];
#pragma unroll
  for (int j = 0; j < 8; j++) {
    const int gc = bn * BNT + n0 + j;
    bb[j] = bias0[gc] + bias1[gc];
  }
#pragma unroll
  for (int i = 0; i < 8; i++) {
    const size_t off = (size_t)(bm * BMT + m0 + i) * G4 + bn * BNT + n0;
    float4 v0, v1;
    v0.x = acc[i][0] + bb[0]; v0.y = acc[i][1] + bb[1]; v0.z = acc[i][2] + bb[2]; v0.w = acc[i][3] + bb[3];
    v1.x = acc[i][4] + bb[4]; v1.y = acc[i][5] + bb[5]; v1.z = acc[i][6] + bb[6]; v1.w = acc[i][7] + bb[7];
    *(float4*)&g_xg[off]     = v0;
    *(float4*)&g_xg[off + 4] = v1;
  }
}

// ---------------- K2: persistent LSTM, 1 wave = 1 unit, registers only ---------
// 1024 WGs x 64 threads. Wave owns unit u = blockIdx.x. Lane l: gate g = l>>4,
// col segment j = l&15 (64 cols = 16 f32x4). Weights 16 f32x4 in VGPRs.
// h consumed straight from global (NaN-sentinel), no LDS, no syncthreads.

__global__ __launch_bounds__(64) void k_lstm(
    const float* __restrict__ bot_Whh,
    const float* __restrict__ top_Wih, const float* __restrict__ top_Whh,
    const float* __restrict__ top_bih, const float* __restrict__ top_bhh,
    const float* __restrict__ hw_b,    const float* __restrict__ cw_w,
    const float* __restrict__ cw_b,    const float* __restrict__ att_bias)
{
  const int u  = blockIdx.x;            // owned hidden unit 0..1023
  const int l  = threadIdx.x;           // 0..63
  const int g  = l >> 4;                // gate 0..3
  const int j  = l & 15;                // col segment 0..15
  const int row = (g << 10) + u;        // gate*1024 + unit

  __shared__ float xg2[UPL][4];         // top-LSTM input preactivations (1 wave)

  f32x4 wv[16];
  load_w16(wv, bot_Whh, row, j);

  float cst = 0.f;
  float xv = (j == 0) ? g_xg[row] : 0.f;   // step 0 xval

  // ---- bottom LSTM: 4096 sequential steps ----
  for (int step = 0; step < SEQ; step++) {
    // prefetch next xval early (latency hidden under poll+dot)
    float xvn = 0.f;
    if (j == 0) {
      const int ns = (step + 1 < SEQ) ? step + 1 : SEQ - 1;
      xvn = g_xg[((size_t)ns << 12) + row];
    }

    float acc;
    if (step == 0) {
      acc = xv;
    } else {
      acc = poll_dot<8>(g_hs + ((size_t)(step - 1) << 10) + (j << 6), wv, xv);
    }
#pragma unroll
    for (int m = 1; m < 16; m <<= 1) acc += __shfl_xor(acc, m);

    const float gi = __shfl(acc, 0);
    const float gf = __shfl(acc, 16);
    const float gg = __shfl(acc, 32);
    const float go = __shfl(acc, 48);
    const float ii = 1.f / (1.f + expf(-gi));
    const float ff = 1.f / (1.f + expf(-gf));
    cst = ff * cst + ii * tanhf(gg);
    const float hh = (1.f / (1.f + expf(-go))) * tanhf(cst);

    if (l == 0) {
      sc_store1(&g_hs[((size_t)step << 10) + u], hh);      // coherent publish
      g_y[((size_t)step << 10) + u] = hh;                  // plain, later kernels
      if ((step & 63) == 63)
        sc_store1(&g_upxs[((size_t)(step >> 6) << 10) + u], hh);
    }
    xv = xvn;
  }

  // ---- top-LSTM input projection: xg2[s] = upx[s] @ top_Wih^T + bias ----
  load_w16(wv, top_Wih, row, j);
  const float tb = (j == 0) ? (top_bih[row] + top_bhh[row]) : 0.f;
  for (int s = 0; s < UPL; s++) {
    float acc = poll_dot<0>(g_upxs + ((size_t)s << 10) + (j << 6), wv, tb);
#pragma unroll
    for (int m = 1; m < 16; m <<= 1) acc += __shfl_xor(acc, m);
    if (j == 0) xg2[s][g] = acc;
  }

  // ---- top recurrence: 64 steps ----
  load_w16(wv, top_Whh, row, j);
  cst = 0.f;
  for (int s = 0; s < UPL; s++) {
    float acc;
    if (s == 0) {
      acc = 0.f;
    } else {
      acc = poll_dot<2>(g_h2s + ((size_t)(s - 1) << 10) + (j << 6), wv, 0.f);
#pragma unroll
      for (int m = 1; m < 16; m <<= 1) acc += __shfl_xor(acc, m);
    }
    acc += xg2[s][g];                      // uniform within 16-lane group

    const float gi = __shfl(acc, 0);
    const float gf = __shfl(acc, 16);
    const float gg = __shfl(acc, 32);
    const float go = __shfl(acc, 48);
    const float ii = 1.f / (1.f + expf(-gi));
    const float ff = 1.f / (1.f + expf(-gf));
    cst = ff * cst + ii * tanhf(gg);
    const float hh = (1.f / (1.f + expf(-go))) * tanhf(cst);
    if (l == 0)
      sc_store1(&g_h2s[((size_t)s << 10) + u], hh);
  }

  // ---- bias2[u] = hw_b + cw_b + att_bias + ctx @ cw_w^T (ctx = h2[63]) ----
  {
    const float* hb = g_h2s + ((size_t)63 << 10) + (l << 4);
    f32x4 h0 = *(const f32x4*)(hb + 0);
    f32x4 h1 = *(const f32x4*)(hb + 4);
    f32x4 h2 = *(const f32x4*)(hb + 8);
    f32x4 h3 = *(const f32x4*)(hb + 12);
    const float* cr = cw_w + (size_t)u * HID + (l << 4);
    const f32x4 c0 = *(const f32x4*)(cr + 0);
    const f32x4 c1 = *(const f32x4*)(cr + 4);
    const f32x4 c2 = *(const f32x4*)(cr + 8);
    const f32x4 c3 = *(const f32x4*)(cr + 12);
    f32x4 a = c0 * h0 + c1 * h1 + c2 * h2 + c3 * h3;
    float acc = (a.x + a.y) + (a.z + a.w);
    while (__any(acc != acc)) {
      __builtin_amdgcn_s_sleep(2);
      if (nan4(h0)) h0 = sc_load4(hb + 0);
      if (nan4(h1)) h1 = sc_load4(hb + 4);
      if (nan4(h2)) h2 = sc_load4(hb + 8);
      if (nan4(h3)) h3 = sc_load4(hb + 12);
      a = c0 * h0 + c1 * h1 + c2 * h2 + c3 * h3;
      acc = (a.x + a.y) + (a.z + a.w);
    }
#pragma unroll
    for (int m = 1; m < 64; m <<= 1) acc += __shfl_xor(acc, m);
    if (l == 0) g_bias2[u] = acc + hw_b[u] + cw_b[u] + att_bias[u];
  }
}

// ---------------- K3: e[t] = sum_j v2s_w[j]*tanh(y_t . hw_w[j] + bias2[j]) ----
__global__ __launch_bounds__(256) void k_attn_e(const float* __restrict__ hw_w,
                                                const float* __restrict__ v2s_w,
                                                const float* __restrict__ v2s_b)
{
  __shared__ float ys[16][1028];
  __shared__ float ws[16][1028];
  const int b  = blockIdx.x;
  const int t  = threadIdx.x;
  const int rg = t >> 6;
  const int fg = (t >> 4) & 3;
  const int ks = t & 15;

#pragma unroll
  for (int i = 0; i < 16; i++) {
    const int idx = i * 256 + t;
    const int r   = idx >> 8;
    const int c4  = (idx & 255) << 2;
    *(float4*)&ys[r][c4] = *(const float4*)&g_y[(size_t)((b << 4) + r) * HID + c4];
  }

  float e_acc[4] = {0.f, 0.f, 0.f, 0.f};
  for (int f0 = 0; f0 < HID; f0 += 16) {
    __syncthreads();
#pragma unroll
    for (int i = 0; i < 16; i++) {
      const int idx = i * 256 + t;
      const int r   = idx >> 8;
      const int c4  = (idx & 255) << 2;
      *(float4*)&ws[r][c4] = *(const float4*)&hw_w[(size_t)(f0 + r) * HID + c4];
    }
    __syncthreads();

    float acc[4][4];
#pragma unroll
    for (int u = 0; u < 4; u++)
#pragma unroll
      for (int v = 0; v < 4; v++) acc[u][v] = 0.f;

#pragma unroll
    for (int m = 0; m < 16; m++) {
      const int k4 = (ks << 6) + (((m + ks) & 15) << 2);
      float4 av[4], bv[4];
#pragma unroll
      for (int u = 0; u < 4; u++) av[u] = *(const float4*)&ys[(rg << 2) + u][k4];
#pragma unroll
      for (int v = 0; v < 4; v++) bv[v] = *(const float4*)&ws[(fg << 2) + v][k4];
#pragma unroll
      for (int u = 0; u < 4; u++)
#pragma unroll
        for (int v = 0; v < 4; v++) {
          acc[u][v] = fmaf(av[u].x, bv[v].x, acc[u][v]);
          acc[u][v] = fmaf(av[u].y, bv[v].y, acc[u][v]);
          acc[u][v] = fmaf(av[u].z, bv[v].z, acc[u][v]);
          acc[u][v] = fmaf(av[u].w, bv[v].w, acc[u][v]);
        }
    }
#pragma unroll
    for (int u = 0; u < 4; u++)
#pragma unroll
      for (int v = 0; v < 4; v++) {
        float s2 = acc[u][v];
        s2 += __shfl_xor(s2, 8);
        s2 += __shfl_xor(s2, 4);
        s2 += __shfl_xor(s2, 2);
        s2 += __shfl_xor(s2, 1);
        acc[u][v] = s2;
      }
    if (ks == 0) {
#pragma unroll
      for (int v = 0; v < 4; v++) {
        const int jj = f0 + (fg << 2) + v;
        const float bias = g_bias2[jj];
        const float vw   = v2s_w[jj];
#pragma unroll
        for (int u = 0; u < 4; u++)
          e_acc[u] += vw * tanhf(acc[u][v] + bias);
      }
    }
  }
#pragma unroll
  for (int u = 0; u < 4; u++) {
    float s2 = e_acc[u];
    s2 += __shfl_xor(s2, 16);
    s2 += __shfl_xor(s2, 32);
    if (fg == 0 && ks == 0) g_e[(b << 4) + (rg << 2) + u] = s2 + v2s_b[0];
  }
}

// ---------------- K4a: p = exp(e - max e); invden = 1/cumsum(p) --------------
__global__ __launch_bounds__(1024) void k_softmax()
{
  const int t  = threadIdx.x;
  const int ln = t & 63;
  const int wv = t >> 6;
  __shared__ float sred[16];
  __shared__ float soff[16];
  __shared__ float sM;

  const float4 ev = *(const float4*)&g_e[t << 2];
  float mx = fmaxf(fmaxf(ev.x, ev.y), fmaxf(ev.z, ev.w));
#pragma unroll
  for (int d = 32; d >= 1; d >>= 1) mx = fmaxf(mx, __shfl_xor(mx, d));
  if (ln == 0) sred[wv] = mx;
  __syncthreads();
  if (t == 0) {
    float m2 = sred[0];
    for (int i = 1; i < 16; i++) m2 = fmaxf(m2, sred[i]);
    sM = m2;
  }
  __syncthreads();
  const float M = sM;
  float4 pv;
  pv.x = expf(ev.x - M); pv.y = expf(ev.y - M); pv.z = expf(ev.z - M); pv.w = expf(ev.w - M);
  *(float4*)&g_p[t << 2] = pv;

  const float s = pv.x + pv.y + pv.z + pv.w;
  float ps = s;
#pragma unroll
  for (int d = 1; d < 64; d <<= 1) {
    const float v = __shfl_up(ps, d);
    if (ln >= d) ps += v;
  }
  __syncthreads();
  if (ln == 63) sred[wv] = ps;
  __syncthreads();
  if (t == 0) {
    float r = 0.f;
    for (int i = 0; i < 16; i++) { soff[i] = r; r += sred[i]; }
  }
  __syncthreads();
  const float base = soff[wv] + (ps - s);
  const float d0 = base + pv.x;
  const float d1 = d0 + pv.y;
  const float d2 = d1 + pv.z;
  const float d3 = d2 + pv.w;
  float4 iv;
  iv.x = 1.f / d0; iv.y = 1.f / d1; iv.z = 1.f / d2; iv.w = 1.f / d3;
  *(float4*)&g_invden[t << 2] = iv;
}

// ---------------- K4b/c/d: chunked column scan of cumsum(p*y)/den ------------
__global__ __launch_bounds__(256) void k_csum()
{
  const int ch = blockIdx.x;
  const int t  = threadIdx.x;
  float ax = 0.f, ay = 0.f, az = 0.f, aw = 0.f;
  for (int r = 0; r < 64; r++) {
    const int row = (ch << 6) + r;
    const float pr = g_p[row];
    const float4 yv = *(const float4*)&g_y[(size_t)row * HID + (t << 2)];
    ax = fmaf(pr, yv.x, ax); ay = fmaf(pr, yv.y, ay);
    az = fmaf(pr, yv.z, az); aw = fmaf(pr, yv.w, aw);
  }
  float4 o; o.x = ax; o.y = ay; o.z = az; o.w = aw;
  *(float4*)&g_csum[(ch << 10) + (t << 2)] = o;
}

__global__ __launch_bounds__(256) void k_cscan()
{
  const int c = blockIdx.x * 256 + threadIdx.x;
  float run = 0.f;
  for (int ch = 0; ch < 64; ch++) {
    const float v = g_csum[(ch << 10) + c];
    g_csum[(ch << 10) + c] = run;
    run += v;
  }
}

__global__ __launch_bounds__(256) void k_final(float* __restrict__ out)
{
  const int ch = blockIdx.x;
  const int t  = threadIdx.x;
  float4 run = *(const float4*)&g_csum[(ch << 10) + (t << 2)];
  for (int r = 0; r < 64; r++) {
    const int row = (ch << 6) + r;
    const float pr = g_p[row];
    const float iv = g_invden[row];
    const float4 yv = *(const float4*)&g_y[(size_t)row * HID + (t << 2)];
    run.x = fmaf(pr, yv.x, run.x);
    run.y = fmaf(pr, yv.y, run.y);
    run.z = fmaf(pr, yv.z, run.z);
    run.w = fmaf(pr, yv.w, run.w);
    float4 ov;
    ov.x = run.x * iv; ov.y = run.y * iv; ov.z = run.z * iv; ov.w = run.w * iv;
    *(float4*)&out[(size_t)row * HID + (t << 2)] = ov;
  }
}

// ---------------- host launch --------------------------------------------------
extern "C" void kernel_launch(void* const* d_in, const int* in_sizes, int n_in,
                              void* d_out, int out_size, void* d_ws, size_t ws_size,
                              hipStream_t stream)
{
  (void)in_sizes; (void)n_in; (void)d_ws; (void)ws_size; (void)out_size;

  const float* x        = (const float*)d_in[0];
  const float* bot_Wih  = (const float*)d_in[1];
  const float* bot_Whh  = (const float*)d_in[2];
  const float* bot_bih  = (const float*)d_in[3];
  const float* bot_bhh  = (const float*)d_in[4];
  const float* top_Wih  = (const float*)d_in[5];
  const float* top_Whh  = (const float*)d_in[6];
  const float* top_bih  = (const float*)d_in[7];
  const float* top_bhh  = (const float*)d_in[8];
  const float* hw_w     = (const float*)d_in[9];
  const float* hw_b     = (const float*)d_in[10];
  const float* cw_w     = (const float*)d_in[11];
  const float* cw_b     = (const float*)d_in[12];
  const float* att_bias = (const float*)d_in[13];
  const float* v2s_w    = (const float*)d_in[14];
  const float* v2s_b    = (const float*)d_in[15];
  float* out = (float*)d_out;

  k_init<<<dim3(4096), dim3(256), 0, stream>>>();
  k_gemm_xg<<<dim3(32, 32), dim3(256), 0, stream>>>(x, bot_Wih, bot_bih, bot_bhh);
  k_lstm<<<dim3(1024), dim3(64), 0, stream>>>(bot_Whh, top_Wih, top_Whh,
                                              top_bih, top_bhh,
                                              hw_b, cw_w, cw_b, att_bias);
  k_attn_e<<<dim3(256), dim3(256), 0, stream>>>(hw_w, v2s_w, v2s_b);
  k_softmax<<<dim3(1), dim3(1024), 0, stream>>>();
  k_csum<<<dim3(64), dim3(256), 0, stream>>>();
  k_cscan<<<dim3(4), dim3(256), 0, stream>>>();
  k_final<<<dim3(64), dim3(256), 0, stream>>>(out);
}

// Round 12
// 11635.464 us; speedup vs baseline: 2.6458x; 2.6458x over previous
//
#include <hip/hip_runtime.h>
#include <hip/hip_bf16.h>
#include <cstdint>
#include <cstddef>

#define SEQ 4096
#define HID 1024
#define G4  4096
#define NWG 128      // 128 WGs x 256 threads; WG owns 8 units (2 per wave)
#define TPB 256
#define UPL 64

typedef float f32x4 __attribute__((ext_vector_type(4)));
typedef float f32x2 __attribute__((ext_vector_type(2)));

// ---------------- persistent device scratch ------------------------------------
__device__ float g_xg  [(size_t)SEQ * G4];   // 64 MB: input preactivations
__device__ float g_y   [(size_t)SEQ * HID];  // 16 MB: bottom LSTM outputs
__device__ float g_hs  [(size_t)SEQ * HID];  // 16 MB: h per step (NaN-sentinel)
__device__ float g_upxs[(size_t)UPL * HID];  // sampled y rows (NaN-sentinel)
__device__ float g_h2s [(size_t)UPL * HID];  // top LSTM h per step (NaN-sentinel)
__device__ float g_bias2[HID];
__device__ float g_e[SEQ];
__device__ float g_p[SEQ];
__device__ float g_invden[SEQ];
__device__ float g_csum[64 * HID];

// NaN-fill all sentinel buffers each launch (kernel-boundary ordering makes the
// fill visible device-wide before k_lstm; no cross-call state relied upon).
__global__ __launch_bounds__(256) void k_init()
{
  const size_t i = (size_t)blockIdx.x * 256 + threadIdx.x;   // 1M threads
  const unsigned Q = 0x7fc00000u;
  const uint4 nan4v = {Q, Q, Q, Q};
  ((uint4*)g_hs)[i] = nan4v;                                 // exactly 16 MB
  if (i < (size_t)UPL * HID / 4) {
    ((uint4*)g_upxs)[i] = nan4v;
    ((uint4*)g_h2s)[i]  = nan4v;
  }
}

// -------- coherent ops at the chip coherence point ------------------------------
__device__ __forceinline__ void sc_store2(float* p, f32x2 v) {
  asm volatile("global_store_dwordx2 %0, %1, off sc0 sc1" :: "v"(p), "v"(v) : "memory");
}
__device__ __forceinline__ f32x4 sc_load4(const float* p) {
  f32x4 v;
  asm volatile("global_load_dwordx4 %0, %1, off sc0 sc1\n\t"
               "s_waitcnt vmcnt(0)" : "=&v"(v) : "v"(p));
  return v;
}
__device__ __forceinline__ int nan4(f32x4 c) {
  return (c.x != c.x) | (c.y != c.y) | (c.z != c.z) | (c.w != c.w);
}
__device__ __forceinline__ float sigf(float x) { return 1.f / (1.f + expf(-x)); }

// NaN-sentinel staging: thread loads 4 consecutive floats (fresh address ->
// plain coalesced load), single check, sc0sc1-reload fallback, write to LDS.
template<int SL>
__device__ __forceinline__ void stage4(const float* __restrict__ src,
                                       float* __restrict__ dst)
{
  if (SL) __builtin_amdgcn_s_sleep(SL);
  asm volatile("" ::: "memory");
  f32x4 c = *(const f32x4*)src;
  while (__any(nan4(c))) {
    __builtin_amdgcn_s_sleep(2);
    if (nan4(c)) c = sc_load4(src);
  }
  *(f32x4*)dst = c;
}

__device__ __forceinline__ void load_w16(f32x4* __restrict__ wv,
                                         const float* __restrict__ W,
                                         int row, int j)
{
  const float* wr = W + (size_t)row * HID + (j << 6);
#pragma unroll
  for (int k = 0; k < 16; k++) wv[k] = *(const f32x4*)&wr[((k + j) & 15) << 2];
}

// ---------------- K1: xg = x @ bot_Wih^T + (bih + bhh), fp32 tiled GEMM --------
#define BMT 128
#define BNT 128
#define BKT 32

__global__ __launch_bounds__(256) void k_gemm_xg(const float* __restrict__ A,
                                                 const float* __restrict__ B,
                                                 const float* __restrict__ bias0,
                                                 const float* __restrict__ bias1)
{
  __shared__ float As[BKT][BMT + 4];
  __shared__ float Bs[BKT][BNT + 4];
  const int t  = threadIdx.x;
  const int bn = blockIdx.x;
  const int bm = blockIdx.y;
  const int m0 = (t & 15) * 8;
  const int n0 = (t >> 4) * 8;

  float acc[8][8];
#pragma unroll
  for (int i = 0; i < 8; i++)
#pragma unroll
    for (int j = 0; j < 8; j++) acc[i][j] = 0.f;

  for (int k0 = 0; k0 < 1024; k0 += BKT) {
#pragma unroll
    for (int i = 0; i < 4; i++) {
      const int idx = i * 256 + t;
      const int m   = idx >> 3;
      const int k4  = (idx & 7) << 2;
      const float4 av = *(const float4*)&A[(size_t)(bm * BMT + m) * 1024 + k0 + k4];
      As[k4 + 0][m] = av.x; As[k4 + 1][m] = av.y; As[k4 + 2][m] = av.z; As[k4 + 3][m] = av.w;
      const float4 bv = *(const float4*)&B[(size_t)(bn * BNT + m) * 1024 + k0 + k4];
      Bs[k4 + 0][m] = bv.x; Bs[k4 + 1][m] = bv.y; Bs[k4 + 2][m] = bv.z; Bs[k4 + 3][m] = bv.w;
    }
    __syncthreads();
#pragma unroll
    for (int k = 0; k < BKT; k++) {
      float a[8], b[8];
      *(float4*)&a[0] = *(const float4*)&As[k][m0];
      *(float4*)&a[4] = *(const float4*)&As[k][m0 + 4];
      *(float4*)&b[0] = *(const float4*)&Bs[k][n0];
      *(float4*)&b[4] = *(const float4*)&Bs[k][n0 + 4];
#pragma unroll
      for (int i = 0; i < 8; i++)
#pragma unroll
        for (int j = 0; j < 8; j++) acc[i][j] = fmaf(a[i], b[j], acc[i][j]);
    }
    __syncthreads();
  }

  float bb[8];
#pragma unroll
  for (int j = 0; j < 8; j++) {
    const int gc = bn * BNT + n0 + j;
    bb[j] = bias0[gc] + bias1[gc];
  }
#pragma unroll
  for (int i = 0; i < 8; i++) {
    const size_t off = (size_t)(bm * BMT + m0 + i) * G4 + bn * BNT + n0;
    float4 v0, v1;
    v0.x = acc[i][0] + bb[0]; v0.y = acc[i][1] + bb[1]; v0.z = acc[i][2] + bb[2]; v0.w = acc[i][3] + bb[3];
    v1.x = acc[i][4] + bb[4]; v1.y = acc[i][5] + bb[5]; v1.z = acc[i][6] + bb[6]; v1.w = acc[i][7] + bb[7];
    *(float4*)&g_xg[off]     = v0;
    *(float4*)&g_xg[off + 4] = v1;
  }
}

// ---------------- K2: persistent LSTM, 2 units/wave + NaN-sentinel dataflow ----
// 128 WGs x 256 threads (4 waves). Wave q of WG w owns units u0=8w+2q, u0+1.
// Lane l: gate g=l>>4, col segment j=l&15 (64 cols = 16 f32x4, rotated).
// Weights: 2 rows x 16 f32x4 = 128 VGPRs. h staged to LDS once, read as b128,
// each read feeds BOTH rows (2x register reuse -> half the DS-pipe time).

__global__ __launch_bounds__(TPB) void k_lstm(
    const float* __restrict__ bot_Whh,
    const float* __restrict__ top_Wih, const float* __restrict__ top_Whh,
    const float* __restrict__ top_bih, const float* __restrict__ top_bhh,
    const float* __restrict__ hw_b,    const float* __restrict__ cw_w,
    const float* __restrict__ cw_b,    const float* __restrict__ att_bias)
{
  const int w  = blockIdx.x;            // 0..127
  const int t  = threadIdx.x;           // 0..255
  const int q  = t >> 6;                // wave 0..3
  const int l  = t & 63;
  const int g  = l >> 4;                // gate 0..3
  const int j  = l & 15;                // col segment 0..15
  const int u0 = (w << 3) + (q << 1);   // first of 2 owned units (even)
  const int row0 = (g << 10) + u0;      // gate*1024 + u0

  __shared__ float hbuf[2][HID];        // parity-double-buffered h stage
  __shared__ float xg2s[UPL][4][4][2];  // [s][wave][gate][unit]

  f32x4 w0[16], w1[16];
  load_w16(w0, bot_Whh, row0, j);
  load_w16(w1, bot_Whh, row0 + 1, j);

  float cst0 = 0.f, cst1 = 0.f;
  float xv0 = 0.f, xv1 = 0.f;
  if (j == 0) {
    const f32x2 x2 = *(const f32x2*)&g_xg[row0];
    xv0 = x2.x; xv1 = x2.y;
  }

  // ---- bottom LSTM: 4096 sequential steps, ONE barrier per step ----
  for (int step = 0; step < SEQ; step++) {
    if (step == 0) {
      const f32x4 z = {0.f, 0.f, 0.f, 0.f};
      *(f32x4*)&hbuf[0][t << 2] = z;
    } else {
      stage4<8>(&g_hs[((size_t)(step - 1) << 10) + (t << 2)],
                &hbuf[step & 1][t << 2]);
    }
    __syncthreads();

    // prefetch next xval (hidden under the dot)
    float nx0 = 0.f, nx1 = 0.f;
    if (j == 0) {
      const int ns = (step + 1 < SEQ) ? step + 1 : SEQ - 1;
      const f32x2 nx = *(const f32x2*)&g_xg[((size_t)ns << 12) + row0];
      nx0 = nx.x; nx1 = nx.y;
    }

    const float* hb = &hbuf[step & 1][j << 6];
    f32x4 a0 = {0.f,0.f,0.f,0.f}, a1 = {0.f,0.f,0.f,0.f};
#pragma unroll
    for (int k = 0; k < 16; k++) {
      const f32x4 hv = *(const f32x4*)&hb[((k + j) & 15) << 2];
      a0 += w0[k] * hv;
      a1 += w1[k] * hv;
    }
    float r0 = (a0.x + a0.y) + (a0.z + a0.w) + xv0;   // xv==0 on j!=0 lanes
    float r1 = (a1.x + a1.y) + (a1.z + a1.w) + xv1;
#pragma unroll
    for (int m = 1; m < 16; m <<= 1) {
      r0 += __shfl_xor(r0, m);
      r1 += __shfl_xor(r1, m);
    }

    const float gi0 = __shfl(r0, 0),  gi1 = __shfl(r1, 0);
    const float gf0 = __shfl(r0, 16), gf1 = __shfl(r1, 16);
    const float gg0 = __shfl(r0, 32), gg1 = __shfl(r1, 32);
    const float go0 = __shfl(r0, 48), go1 = __shfl(r1, 48);
    cst0 = sigf(gf0) * cst0 + sigf(gi0) * tanhf(gg0);
    cst1 = sigf(gf1) * cst1 + sigf(gi1) * tanhf(gg1);
    const float h0 = sigf(go0) * tanhf(cst0);
    const float h1 = sigf(go1) * tanhf(cst1);

    if (l == 0) {
      f32x2 hp; hp.x = h0; hp.y = h1;
      sc_store2(&g_hs[((size_t)step << 10) + u0], hp);   // coherent publish
      *(f32x2*)&g_y[((size_t)step << 10) + u0] = hp;     // plain, later kernels
      if ((step & 63) == 63)
        sc_store2(&g_upxs[((size_t)(step >> 6) << 10) + u0], hp);
    }
    xv0 = nx0; xv1 = nx1;
  }

  // ---- top-LSTM input projection: xg2[s] = upx[s] @ top_Wih^T + bias ----
  load_w16(w0, top_Wih, row0, j);
  load_w16(w1, top_Wih, row0 + 1, j);
  float tb0 = 0.f, tb1 = 0.f;
  if (j == 0) {
    tb0 = top_bih[row0] + top_bhh[row0];
    tb1 = top_bih[row0 + 1] + top_bhh[row0 + 1];
  }
  for (int s = 0; s < UPL; s++) {
    stage4<0>(&g_upxs[((size_t)s << 10) + (t << 2)], &hbuf[s & 1][t << 2]);
    __syncthreads();
    const float* hb = &hbuf[s & 1][j << 6];
    f32x4 a0 = {0.f,0.f,0.f,0.f}, a1 = {0.f,0.f,0.f,0.f};
#pragma unroll
    for (int k = 0; k < 16; k++) {
      const f32x4 hv = *(const f32x4*)&hb[((k + j) & 15) << 2];
      a0 += w0[k] * hv;
      a1 += w1[k] * hv;
    }
    float r0 = (a0.x + a0.y) + (a0.z + a0.w) + tb0;
    float r1 = (a1.x + a1.y) + (a1.z + a1.w) + tb1;
#pragma unroll
    for (int m = 1; m < 16; m <<= 1) {
      r0 += __shfl_xor(r0, m);
      r1 += __shfl_xor(r1, m);
    }
    if (j == 0) {
      xg2s[s][q][g][0] = r0;
      xg2s[s][q][g][1] = r1;
    }
  }

  // ---- top recurrence: 64 steps ----
  load_w16(w0, top_Whh, row0, j);
  load_w16(w1, top_Whh, row0 + 1, j);
  cst0 = 0.f; cst1 = 0.f;
  for (int s = 0; s < UPL; s++) {
    if (s == 0) {
      const f32x4 z = {0.f, 0.f, 0.f, 0.f};
      *(f32x4*)&hbuf[0][t << 2] = z;
    } else {
      stage4<2>(&g_h2s[((size_t)(s - 1) << 10) + (t << 2)],
                &hbuf[s & 1][t << 2]);
    }
    __syncthreads();
    const float* hb = &hbuf[s & 1][j << 6];
    f32x4 a0 = {0.f,0.f,0.f,0.f}, a1 = {0.f,0.f,0.f,0.f};
#pragma unroll
    for (int k = 0; k < 16; k++) {
      const f32x4 hv = *(const f32x4*)&hb[((k + j) & 15) << 2];
      a0 += w0[k] * hv;
      a1 += w1[k] * hv;
    }
    float r0 = (a0.x + a0.y) + (a0.z + a0.w);
    float r1 = (a1.x + a1.y) + (a1.z + a1.w);
#pragma unroll
    for (int m = 1; m < 16; m <<= 1) {
      r0 += __shfl_xor(r0, m);
      r1 += __shfl_xor(r1, m);
    }
    r0 += xg2s[s][q][g][0];                 // uniform within 16-lane group
    r1 += xg2s[s][q][g][1];

    const float gi0 = __shfl(r0, 0),  gi1 = __shfl(r1, 0);
    const float gf0 = __shfl(r0, 16), gf1 = __shfl(r1, 16);
    const float gg0 = __shfl(r0, 32), gg1 = __shfl(r1, 32);
    const float go0 = __shfl(r0, 48), go1 = __shfl(r1, 48);
    cst0 = sigf(gf0) * cst0 + sigf(gi0) * tanhf(gg0);
    cst1 = sigf(gf1) * cst1 + sigf(gi1) * tanhf(gg1);
    const float h0 = sigf(go0) * tanhf(cst0);
    const float h1 = sigf(go1) * tanhf(cst1);
    if (l == 0) {
      f32x2 hp; hp.x = h0; hp.y = h1;
      sc_store2(&g_h2s[((size_t)s << 10) + u0], hp);
    }
  }

  // ---- bias2[u] = hw_b + cw_b + att_bias + ctx @ cw_w^T (ctx = h2[63]) ----
  stage4<2>(&g_h2s[((size_t)63 << 10) + (t << 2)], &hbuf[0][t << 2]);
  __syncthreads();
  {
    const float* hb2 = &hbuf[0][l << 4];     // lane l: cols [16l, 16l+16)
    const float* cr0 = cw_w + (size_t)u0 * HID + (l << 4);
    const float* cr1 = cw_w + (size_t)(u0 + 1) * HID + (l << 4);
    f32x4 a0 = {0.f,0.f,0.f,0.f}, a1 = {0.f,0.f,0.f,0.f};
#pragma unroll
    for (int k = 0; k < 4; k++) {
      const f32x4 hv = *(const f32x4*)&hb2[k << 2];
      a0 += (*(const f32x4*)&cr0[k << 2]) * hv;
      a1 += (*(const f32x4*)&cr1[k << 2]) * hv;
    }
    float r0 = (a0.x + a0.y) + (a0.z + a0.w);
    float r1 = (a1.x + a1.y) + (a1.z + a1.w);
#pragma unroll
    for (int m = 1; m < 64; m <<= 1) {
      r0 += __shfl_xor(r0, m);
      r1 += __shfl_xor(r1, m);
    }
    if (l == 0) {
      g_bias2[u0]     = r0 + hw_b[u0]     + cw_b[u0]     + att_bias[u0];
      g_bias2[u0 + 1] = r1 + hw_b[u0 + 1] + cw_b[u0 + 1] + att_bias[u0 + 1];
    }
  }
}

// ---------------- K3: e[t] = sum_j v2s_w[j]*tanh(y_t . hw_w[j] + bias2[j]) ----
__global__ __launch_bounds__(256) void k_attn_e(const float* __restrict__ hw_w,
                                                const float* __restrict__ v2s_w,
                                                const float* __restrict__ v2s_b)
{
  __shared__ float ys[16][1028];
  __shared__ float ws[16][1028];
  const int b  = blockIdx.x;
  const int t  = threadIdx.x;
  const int rg = t >> 6;
  const int fg = (t >> 4) & 3;
  const int ks = t & 15;

#pragma unroll
  for (int i = 0; i < 16; i++) {
    const int idx = i * 256 + t;
    const int r   = idx >> 8;
    const int c4  = (idx & 255) << 2;
    *(float4*)&ys[r][c4] = *(const float4*)&g_y[(size_t)((b << 4) + r) * HID + c4];
  }

  float e_acc[4] = {0.f, 0.f, 0.f, 0.f};
  for (int f0 = 0; f0 < HID; f0 += 16) {
    __syncthreads();
#pragma unroll
    for (int i = 0; i < 16; i++) {
      const int idx = i * 256 + t;
      const int r   = idx >> 8;
      const int c4  = (idx & 255) << 2;
      *(float4*)&ws[r][c4] = *(const float4*)&hw_w[(size_t)(f0 + r) * HID + c4];
    }
    __syncthreads();

    float acc[4][4];
#pragma unroll
    for (int u = 0; u < 4; u++)
#pragma unroll
      for (int v = 0; v < 4; v++) acc[u][v] = 0.f;

#pragma unroll
    for (int m = 0; m < 16; m++) {
      const int k4 = (ks << 6) + (((m + ks) & 15) << 2);
      float4 av[4], bv[4];
#pragma unroll
      for (int u = 0; u < 4; u++) av[u] = *(const float4*)&ys[(rg << 2) + u][k4];
#pragma unroll
      for (int v = 0; v < 4; v++) bv[v] = *(const float4*)&ws[(fg << 2) + v][k4];
#pragma unroll
      for (int u = 0; u < 4; u++)
#pragma unroll
        for (int v = 0; v < 4; v++) {
          acc[u][v] = fmaf(av[u].x, bv[v].x, acc[u][v]);
          acc[u][v] = fmaf(av[u].y, bv[v].y, acc[u][v]);
          acc[u][v] = fmaf(av[u].z, bv[v].z, acc[u][v]);
          acc[u][v] = fmaf(av[u].w, bv[v].w, acc[u][v]);
        }
    }
#pragma unroll
    for (int u = 0; u < 4; u++)
#pragma unroll
      for (int v = 0; v < 4; v++) {
        float s2 = acc[u][v];
        s2 += __shfl_xor(s2, 8);
        s2 += __shfl_xor(s2, 4);
        s2 += __shfl_xor(s2, 2);
        s2 += __shfl_xor(s2, 1);
        acc[u][v] = s2;
      }
    if (ks == 0) {
#pragma unroll
      for (int v = 0; v < 4; v++) {
        const int jj = f0 + (fg << 2) + v;
        const float bias = g_bias2[jj];
        const float vw   = v2s_w[jj];
#pragma unroll
        for (int u = 0; u < 4; u++)
          e_acc[u] += vw * tanhf(acc[u][v] + bias);
      }
    }
  }
#pragma unroll
  for (int u = 0; u < 4; u++) {
    float s2 = e_acc[u];
    s2 += __shfl_xor(s2, 16);
    s2 += __shfl_xor(s2, 32);
    if (fg == 0 && ks == 0) g_e[(b << 4) + (rg << 2) + u] = s2 + v2s_b[0];
  }
}

// ---------------- K4a: p = exp(e - max e); invden = 1/cumsum(p) --------------
__global__ __launch_bounds__(1024) void k_softmax()
{
  const int t  = threadIdx.x;
  const int ln = t & 63;
  const int wv = t >> 6;
  __shared__ float sred[16];
  __shared__ float soff[16];
  __shared__ float sM;

  const float4 ev = *(const float4*)&g_e[t << 2];
  float mx = fmaxf(fmaxf(ev.x, ev.y), fmaxf(ev.z, ev.w));
#pragma unroll
  for (int d = 32; d >= 1; d >>= 1) mx = fmaxf(mx, __shfl_xor(mx, d));
  if (ln == 0) sred[wv] = mx;
  __syncthreads();
  if (t == 0) {
    float m2 = sred[0];
    for (int i = 1; i < 16; i++) m2 = fmaxf(m2, sred[i]);
    sM = m2;
  }
  __syncthreads();
  const float M = sM;
  float4 pv;
  pv.x = expf(ev.x - M); pv.y = expf(ev.y - M); pv.z = expf(ev.z - M); pv.w = expf(ev.w - M);
  *(float4*)&g_p[t << 2] = pv;

  const float s = pv.x + pv.y + pv.z + pv.w;
  float ps = s;
#pragma unroll
  for (int d = 1; d < 64; d <<= 1) {
    const float v = __shfl_up(ps, d);
    if (ln >= d) ps += v;
  }
  __syncthreads();
  if (ln == 63) sred[wv] = ps;
  __syncthreads();
  if (t == 0) {
    float r = 0.f;
    for (int i = 0; i < 16; i++) { soff[i] = r; r += sred[i]; }
  }
  __syncthreads();
  const float base = soff[wv] + (ps - s);
  const float d0 = base + pv.x;
  const float d1 = d0 + pv.y;
  const float d2 = d1 + pv.z;
  const float d3 = d2 + pv.w;
  float4 iv;
  iv.x = 1.f / d0; iv.y = 1.f / d1; iv.z = 1.f / d2; iv.w = 1.f / d3;
  *(float4*)&g_invden[t << 2] = iv;
}

// ---------------- K4b/c/d: chunked column scan of cumsum(p*y)/den ------------
__global__ __launch_bounds__(256) void k_csum()
{
  const int ch = blockIdx.x;
  const int t  = threadIdx.x;
  float ax = 0.f, ay = 0.f, az = 0.f, aw = 0.f;
  for (int r = 0; r < 64; r++) {
    const int row = (ch << 6) + r;
    const float pr = g_p[row];
    const float4 yv = *(const float4*)&g_y[(size_t)row * HID + (t << 2)];
    ax = fmaf(pr, yv.x, ax); ay = fmaf(pr, yv.y, ay);
    az = fmaf(pr, yv.z, az); aw = fmaf(pr, yv.w, aw);
  }
  float4 o; o.x = ax; o.y = ay; o.z = az; o.w = aw;
  *(float4*)&g_csum[(ch << 10) + (t << 2)] = o;
}

__global__ __launch_bounds__(256) void k_cscan()
{
  const int c = blockIdx.x * 256 + threadIdx.x;
  float run = 0.f;
  for (int ch = 0; ch < 64; ch++) {
    const float v = g_csum[(ch << 10) + c];
    g_csum[(ch << 10) + c] = run;
    run += v;
  }
}

__global__ __launch_bounds__(256) void k_final(float* __restrict__ out)
{
  const int ch = blockIdx.x;
  const int t  = threadIdx.x;
  float4 run = *(const float4*)&g_csum[(ch << 10) + (t << 2)];
  for (int r = 0; r < 64; r++) {
    const int row = (ch << 6) + r;
    const float pr = g_p[row];
    const float iv = g_invden[row];
    const float4 yv = *(const float4*)&g_y[(size_t)row * HID + (t << 2)];
    run.x = fmaf(pr, yv.x, run.x);
    run.y = fmaf(pr, yv.y, run.y);
    run.z = fmaf(pr, yv.z, run.z);
    run.w = fmaf(pr, yv.w, run.w);
    float4 ov;
    ov.x = run.x * iv; ov.y = run.y * iv; ov.z = run.z * iv; ov.w = run.w * iv;
    *(float4*)&out[(size_t)row * HID + (t << 2)] = ov;
  }
}

// ---------------- host launch --------------------------------------------------
extern "C" void kernel_launch(void* const* d_in, const int* in_sizes, int n_in,
                              void* d_out, int out_size, void* d_ws, size_t ws_size,
                              hipStream_t stream)
{
  (void)in_sizes; (void)n_in; (void)d_ws; (void)ws_size; (void)out_size;

  const float* x        = (const float*)d_in[0];
  const float* bot_Wih  = (const float*)d_in[1];
  const float* bot_Whh  = (const float*)d_in[2];
  const float* bot_bih  = (const float*)d_in[3];
  const float* bot_bhh  = (const float*)d_in[4];
  const float* top_Wih  = (const float*)d_in[5];
  const float* top_Whh  = (const float*)d_in[6];
  const float* top_bih  = (const float*)d_in[7];
  const float* top_bhh  = (const float*)d_in[8];
  const float* hw_w     = (const float*)d_in[9];
  const float* hw_b     = (const float*)d_in[10];
  const float* cw_w     = (const float*)d_in[11];
  const float* cw_b     = (const float*)d_in[12];
  const float* att_bias = (const float*)d_in[13];
  const float* v2s_w    = (const float*)d_in[14];
  const float* v2s_b    = (const float*)d_in[15];
  float* out = (float*)d_out;

  k_init<<<dim3(4096), dim3(256), 0, stream>>>();
  k_gemm_xg<<<dim3(32, 32), dim3(256), 0, stream>>>(x, bot_Wih, bot_bih, bot_bhh);
  k_lstm<<<dim3(NWG), dim3(TPB), 0, stream>>>(bot_Whh, top_Wih, top_Whh,
                                              top_bih, top_bhh,
                                              hw_b, cw_w, cw_b, att_bias);
  k_attn_e<<<dim3(256), dim3(256), 0, stream>>>(hw_w, v2s_w, v2s_b);
  k_softmax<<<dim3(1), dim3(1024), 0, stream>>>();
  k_csum<<<dim3(64), dim3(256), 0, stream>>>();
  k_cscan<<<dim3(4), dim3(256), 0, stream>>>();
  k_final<<<dim3(64), dim3(256), 0, stream>>>(out);
}